// Round 1
// baseline (320.699 us; speedup 1.0000x reference)
//
#include <hip/hip_runtime.h>
#include <hip/hip_bf16.h>

// Problem constants: E=1024, H=16, HD=64, T=1024, B=4, S=1024.
// d_in: 0 query(T,B,E) f32, 1 key(S,B,E), 2 value(S,B,E), 3 in_proj_weight(3E,E),
//       4 in_proj_bias(3E), 5 out_w(E,E), 6 out_b(E).
// d_out: attn(T,B,E) f32 [4M] then avg_w(B,T,S) f32 [4M].
// ws layout (bytes): qb 0..8M, kb 8M..16M, vb 16M..24M, vT 24M..32M,
//                    attn_b 32M..40M, WT 40M..46M, owb 46M..48M.  (needs 48MB)

typedef __bf16 bf16;
typedef float f32x4 __attribute__((ext_vector_type(4)));
typedef float float4v __attribute__((ext_vector_type(4)));
typedef bf16 bf16x8 __attribute__((ext_vector_type(8)));
typedef bf16 bf16x4 __attribute__((ext_vector_type(4)));

// ---------------- prep kernels ----------------

// dst[sec][j][i] = (bf16) src[sec*1024 + i][j]   (per-1024x1024-section transpose)
__global__ __launch_bounds__(256) void transpose_f32_to_bf16(
    const float* __restrict__ src, bf16* __restrict__ dst, int dim) {
  __shared__ bf16 tile[64][72];
  int sec = blockIdx.z;
  int i0 = blockIdx.y * 64, j0 = blockIdx.x * 64;
  const float* s = src + (long)sec * dim * dim;
  bf16* d = dst + (long)sec * dim * dim;
  int t = threadIdx.x;
#pragma unroll
  for (int p = 0; p < 4; p++) {
    int ri = (t >> 4) + p * 16, cj = (t & 15) * 4;
    float4v v = *(const float4v*)(s + (long)(i0 + ri) * dim + j0 + cj);
    bf16x4 bv = { (bf16)v.x, (bf16)v.y, (bf16)v.z, (bf16)v.w };
    *(bf16x4*)&tile[ri][cj] = bv;
  }
  __syncthreads();
#pragma unroll
  for (int p = 0; p < 4; p++) {
    int rj = (t >> 4) + p * 16, ci = (t & 15) * 4;
    bf16x4 bv = { tile[ci][rj], tile[ci + 1][rj], tile[ci + 2][rj], tile[ci + 3][rj] };
    *(bf16x4*)&d[(long)(j0 + rj) * dim + i0 + ci] = bv;
  }
}

__global__ __launch_bounds__(256) void conv_f32_bf16(
    const float* __restrict__ src, bf16* __restrict__ dst, int n) {
  int i = (blockIdx.x * 256 + threadIdx.x) * 4;
  if (i < n) {
    float4v v = *(const float4v*)(src + i);
    bf16x4 bv = { (bf16)v.x, (bf16)v.y, (bf16)v.z, (bf16)v.w };
    *(bf16x4*)&dst[i] = bv;
  }
}

// vT[(b*1024 + j)*1024 + s] = vb[(s*4 + b)*1024 + j]
__global__ __launch_bounds__(256) void transpose_v(
    const bf16* __restrict__ vb, bf16* __restrict__ vT) {
  __shared__ bf16 tile[64][72];
  int b = blockIdx.z;
  int s0 = blockIdx.x * 64, j0 = blockIdx.y * 64;
  int t = threadIdx.x;
#pragma unroll
  for (int p = 0; p < 2; p++) {
    int si = (t >> 3) + p * 32, jj = (t & 7) * 8;
    bf16x8 v = *(const bf16x8*)&vb[((long)(s0 + si) * 4 + b) * 1024 + j0 + jj];
    *(bf16x8*)&tile[si][jj] = v;
  }
  __syncthreads();
#pragma unroll
  for (int p = 0; p < 2; p++) {
    int jj = (t >> 3) + p * 32, si = (t & 7) * 8;
    bf16 tmp[8];
#pragma unroll
    for (int q = 0; q < 8; q++) tmp[q] = tile[si + q][jj];
    *(bf16x8*)&vT[((long)b * 1024 + j0 + jj) * 1024 + s0 + si] = *(bf16x8*)tmp;
  }
}

// ---------------- generic NT GEMM ----------------
// C[m][n] = scale * ( sum_k A[m][k]*B[n][k] + bias[n] ),  128x128 tile, BK=32.
// A: f32 (converted in staging) or bf16. B: bf16 (N x K row-major). C: f32 or bf16.
template <bool A_F32, bool C_BF16>
__global__ __launch_bounds__(256) void gemm_nt(
    const void* __restrict__ Av, long lda, long sAz,
    const bf16* __restrict__ B, long ldb, long sBz,
    void* __restrict__ Cv, long ldc, long sCz,
    const float* __restrict__ bias, float scale, int K) {
  __shared__ bf16 sA[128][40];  // +8 pad: 2-way-max bank aliasing on b128 reads
  __shared__ bf16 sB[128][40];
  int z = blockIdx.z;
  long aoff = (long)z * sAz, boff = (long)z * sBz, coff = (long)z * sCz;
  int n0 = blockIdx.x * 128, m0 = blockIdx.y * 128;
  int t = threadIdx.x;
  int w = t >> 6, lane = t & 63, r = lane & 15, g = lane >> 4;
  int mq = (w >> 1) * 64, nq = (w & 1) * 64;

  f32x4 acc[4][4];
#pragma unroll
  for (int mi = 0; mi < 4; mi++)
#pragma unroll
    for (int ni = 0; ni < 4; ni++) acc[mi][ni] = (f32x4){0.f, 0.f, 0.f, 0.f};

  for (int k0 = 0; k0 < K; k0 += 32) {
    if (A_F32) {
      const float* Ap = (const float*)Av + aoff;
      int row = t >> 3, col = (t & 7) * 4;
#pragma unroll
      for (int p = 0; p < 4; p++) {
        float4v v = *(const float4v*)(Ap + (long)(m0 + row + p * 32) * lda + k0 + col);
        bf16x4 bv = { (bf16)v.x, (bf16)v.y, (bf16)v.z, (bf16)v.w };
        *(bf16x4*)&sA[row + p * 32][col] = bv;
      }
    } else {
      const bf16* Ap = (const bf16*)Av + aoff;
      int row = t >> 2, col = (t & 3) * 8;
#pragma unroll
      for (int p = 0; p < 2; p++) {
        bf16x8 v = *(const bf16x8*)(Ap + (long)(m0 + row + p * 64) * lda + k0 + col);
        *(bf16x8*)&sA[row + p * 64][col] = v;
      }
    }
    {
      const bf16* Bp = B + boff;
      int row = t >> 2, col = (t & 3) * 8;
#pragma unroll
      for (int p = 0; p < 2; p++) {
        bf16x8 v = *(const bf16x8*)(Bp + (long)(n0 + row + p * 64) * ldb + k0 + col);
        *(bf16x8*)&sB[row + p * 64][col] = v;
      }
    }
    __syncthreads();
    bf16x8 af[4], bfr[4];
#pragma unroll
    for (int mi = 0; mi < 4; mi++) af[mi] = *(bf16x8*)&sA[mq + mi * 16 + r][g * 8];
#pragma unroll
    for (int ni = 0; ni < 4; ni++) bfr[ni] = *(bf16x8*)&sB[nq + ni * 16 + r][g * 8];
#pragma unroll
    for (int mi = 0; mi < 4; mi++)
#pragma unroll
      for (int ni = 0; ni < 4; ni++)
        acc[mi][ni] = __builtin_amdgcn_mfma_f32_16x16x32_bf16(af[mi], bfr[ni], acc[mi][ni], 0, 0, 0);
    __syncthreads();
  }

#pragma unroll
  for (int mi = 0; mi < 4; mi++)
#pragma unroll
    for (int ni = 0; ni < 4; ni++) {
      int col = n0 + nq + ni * 16 + r;
      float bv = bias ? bias[col] : 0.f;
#pragma unroll
      for (int j = 0; j < 4; j++) {
        int row = m0 + mq + mi * 16 + g * 4 + j;
        float val = (acc[mi][ni][j] + bv) * scale;
        if (C_BF16)
          ((bf16*)Cv)[coff + (long)row * ldc + col] = (bf16)val;
        else
          ((float*)Cv)[coff + (long)row * ldc + col] = val;
      }
    }
}

// ---------------- fused dual-softmax flash attention ----------------
// grid (B*H, T/64); 4 waves, wave w owns 16 t-rows. Online softmax for +S and -S.
__global__ __launch_bounds__(256) void attn_fused(
    const bf16* __restrict__ qb, const bf16* __restrict__ kb,
    const bf16* __restrict__ vT, bf16* __restrict__ attn_b) {
  __shared__ bf16 sP[4][16][72];
  int bh = blockIdx.x;
  int b = bh >> 4, h = bh & 15;
  int t0 = blockIdx.y * 64;
  int t = threadIdx.x, w = t >> 6, lane = t & 63, r = lane & 15, g = lane >> 4;
  int tw = t0 + w * 16;

  bf16x8 aq[2];
#pragma unroll
  for (int kk = 0; kk < 2; kk++)
    aq[kk] = *(const bf16x8*)&qb[((long)(tw + r) * 4 + b) * 1024 + h * 64 + kk * 32 + g * 8];

  float m_p[4], l_p[4], m_n[4], l_n[4];
  f32x4 o_p[2], o_n[2];
#pragma unroll
  for (int j = 0; j < 4; j++) { m_p[j] = m_n[j] = -1e30f; l_p[j] = l_n[j] = 0.f; }
#pragma unroll
  for (int ni = 0; ni < 2; ni++) { o_p[ni] = (f32x4){0.f,0.f,0.f,0.f}; o_n[ni] = (f32x4){0.f,0.f,0.f,0.f}; }

  for (int st = 0; st < 16; st++) {
    int sb = st * 64;
    f32x4 sc[4];
#pragma unroll
    for (int sf = 0; sf < 4; sf++) {
      long krow = ((long)(sb + sf * 16 + r) * 4 + b) * 1024 + h * 64;
      bf16x8 k0 = *(const bf16x8*)&kb[krow + g * 8];
      bf16x8 k1 = *(const bf16x8*)&kb[krow + 32 + g * 8];
      f32x4 zz = (f32x4){0.f, 0.f, 0.f, 0.f};
      zz = __builtin_amdgcn_mfma_f32_16x16x32_bf16(aq[0], k0, zz, 0, 0, 0);
      zz = __builtin_amdgcn_mfma_f32_16x16x32_bf16(aq[1], k1, zz, 0, 0, 0);
      sc[sf] = zz;
    }

    float al_p[4], al_n[4], p[4][4], pn[4][4];
#pragma unroll
    for (int j = 0; j < 4; j++) {
      float mx = fmaxf(fmaxf(sc[0][j], sc[1][j]), fmaxf(sc[2][j], sc[3][j]));
      float mn = fminf(fminf(sc[0][j], sc[1][j]), fminf(sc[2][j], sc[3][j]));
#pragma unroll
      for (int d = 1; d < 16; d <<= 1) {
        mx = fmaxf(mx, __shfl_xor(mx, d));
        mn = fminf(mn, __shfl_xor(mn, d));
      }
      float npv = fmaxf(m_p[j], mx);
      float nnv = fmaxf(m_n[j], -mn);
      al_p[j] = __expf(m_p[j] - npv);
      al_n[j] = __expf(m_n[j] - nnv);
      m_p[j] = npv; m_n[j] = nnv;
      float sp = 0.f, sn = 0.f;
#pragma unroll
      for (int sf = 0; sf < 4; sf++) {
        float e1 = __expf(sc[sf][j] - npv); p[sf][j] = e1; sp += e1;
        float e2 = __expf(-sc[sf][j] - nnv); pn[sf][j] = e2; sn += e2;
      }
#pragma unroll
      for (int d = 1; d < 16; d <<= 1) { sp += __shfl_xor(sp, d); sn += __shfl_xor(sn, d); }
      l_p[j] = l_p[j] * al_p[j] + sp;
      l_n[j] = l_n[j] * al_n[j] + sn;
    }
#pragma unroll
    for (int ni = 0; ni < 2; ni++)
#pragma unroll
      for (int j = 0; j < 4; j++) { o_p[ni][j] *= al_p[j]; o_n[ni][j] *= al_n[j]; }

    // ---- corr: P+ through LDS -> A-frag -> PV ----
    __syncthreads();
#pragma unroll
    for (int sf = 0; sf < 4; sf++)
#pragma unroll
      for (int j = 0; j < 4; j++) sP[w][g * 4 + j][sf * 16 + r] = (bf16)p[sf][j];
    __syncthreads();
    {
      bf16x8 ap0 = *(const bf16x8*)&sP[w][r][g * 8];
      bf16x8 ap1 = *(const bf16x8*)&sP[w][r][32 + g * 8];
#pragma unroll
      for (int ni = 0; ni < 2; ni++) {
        long vrow = ((long)b * 1024 + h * 32 + ni * 16 + r) * 1024 + sb;
        bf16x8 v0 = *(const bf16x8*)&vT[vrow + g * 8];
        bf16x8 v1 = *(const bf16x8*)&vT[vrow + 32 + g * 8];
        o_p[ni] = __builtin_amdgcn_mfma_f32_16x16x32_bf16(ap0, v0, o_p[ni], 0, 0, 0);
        o_p[ni] = __builtin_amdgcn_mfma_f32_16x16x32_bf16(ap1, v1, o_p[ni], 0, 0, 0);
      }
    }
    // ---- decorr: P- through LDS -> PV ----
    __syncthreads();
#pragma unroll
    for (int sf = 0; sf < 4; sf++)
#pragma unroll
      for (int j = 0; j < 4; j++) sP[w][g * 4 + j][sf * 16 + r] = (bf16)pn[sf][j];
    __syncthreads();
    {
      bf16x8 ap0 = *(const bf16x8*)&sP[w][r][g * 8];
      bf16x8 ap1 = *(const bf16x8*)&sP[w][r][32 + g * 8];
#pragma unroll
      for (int ni = 0; ni < 2; ni++) {
        long vrow = ((long)b * 1024 + 512 + h * 32 + ni * 16 + r) * 1024 + sb;
        bf16x8 v0 = *(const bf16x8*)&vT[vrow + g * 8];
        bf16x8 v1 = *(const bf16x8*)&vT[vrow + 32 + g * 8];
        o_n[ni] = __builtin_amdgcn_mfma_f32_16x16x32_bf16(ap0, v0, o_n[ni], 0, 0, 0);
        o_n[ni] = __builtin_amdgcn_mfma_f32_16x16x32_bf16(ap1, v1, o_n[ni], 0, 0, 0);
      }
    }
  }

#pragma unroll
  for (int ni = 0; ni < 2; ni++)
#pragma unroll
    for (int j = 0; j < 4; j++) {
      int trow = tw + g * 4 + j;
      attn_b[((long)trow * 4 + b) * 1024 + h * 64 + ni * 16 + r] = (bf16)(o_p[ni][j] / l_p[j]);
      attn_b[((long)trow * 4 + b) * 1024 + h * 64 + 32 + ni * 16 + r] = (bf16)(o_n[ni][j] / l_n[j]);
    }
}

// ---------------- launcher ----------------
extern "C" void kernel_launch(void* const* d_in, const int* in_sizes, int n_in,
                              void* d_out, int out_size, void* d_ws, size_t ws_size,
                              hipStream_t stream) {
  (void)in_sizes; (void)n_in; (void)out_size; (void)ws_size;
  const float* query = (const float*)d_in[0];
  const float* key   = (const float*)d_in[1];
  const float* value = (const float*)d_in[2];
  const float* W     = (const float*)d_in[3];
  const float* bias  = (const float*)d_in[4];
  const float* out_w = (const float*)d_in[5];
  const float* out_b = (const float*)d_in[6];

  char* ws = (char*)d_ws;
  const long MB = 1 << 20;
  bf16* qb  = (bf16*)(ws + 0 * MB);
  bf16* kb  = (bf16*)(ws + 8 * MB);
  bf16* vb  = (bf16*)(ws + 16 * MB);
  bf16* vT  = (bf16*)(ws + 24 * MB);
  bf16* ab  = (bf16*)(ws + 32 * MB);
  bf16* WT  = (bf16*)(ws + 40 * MB);
  bf16* owb = (bf16*)(ws + 46 * MB);
  float* out_attn = (float*)d_out;
  float* out_avg  = (float*)d_out + (size_t)4 * 1024 * 1024;
  const long M1 = 1024L * 1024L;

  transpose_f32_to_bf16<<<dim3(16, 16, 3), 256, 0, stream>>>(W, WT, 1024);
  conv_f32_bf16<<<dim3(1024), 256, 0, stream>>>(out_w, owb, 1024 * 1024);

  // projections: q (scaled by HD^-0.5 = 0.125), k, v
  gemm_nt<true, true><<<dim3(8, 32, 1), 256, 0, stream>>>(
      query, 1024, 0, WT, 1024, 0, qb, 1024, 0, bias, 0.125f, 1024);
  gemm_nt<true, true><<<dim3(8, 32, 1), 256, 0, stream>>>(
      key, 1024, 0, WT + M1, 1024, 0, kb, 1024, 0, bias + 1024, 1.0f, 1024);
  gemm_nt<true, true><<<dim3(8, 32, 1), 256, 0, stream>>>(
      value, 1024, 0, WT + 2 * M1, 1024, 0, vb, 1024, 0, bias + 2048, 1.0f, 1024);

  transpose_v<<<dim3(16, 16, 4), 256, 0, stream>>>(vb, vT);

  // avg_w[b,t,s] = (1/16) * sum_e q_scaled[t,b,e] * k[s,b,e]
  gemm_nt<false, false><<<dim3(8, 8, 4), 256, 0, stream>>>(
      qb, 4096, 1024, kb, 4096, 1024, out_avg, 1024, M1, nullptr, 1.f / 16.f, 1024);

  attn_fused<<<dim3(64, 16), 256, 0, stream>>>(qb, kb, vT, ab);

  // out projection: C = attn @ out_w^T + out_b
  gemm_nt<false, false><<<dim3(8, 32, 1), 256, 0, stream>>>(
      ab, 1024, 0, owb, 1024, 0, out_attn, 1024, 0, out_b, 1.0f, 1024);
}

// Round 2
// 268.985 us; speedup vs baseline: 1.1923x; 1.1923x over previous
//
#include <hip/hip_runtime.h>
#include <hip/hip_bf16.h>

// Problem constants: E=1024, H=16, HD=64, T=1024, B=4, S=1024.
// d_in: 0 query(T,B,E) f32, 1 key(S,B,E), 2 value(S,B,E), 3 in_proj_weight(3E,E),
//       4 in_proj_bias(3E), 5 out_w(E,E), 6 out_b(E).
// d_out: attn(T,B,E) f32 [4M] then avg_w(B,T,S) f32 [4M].
// ws layout (bytes): qb 0..8M, kb 8M..16M, vb 16M..24M, vT 24M..32M,
//                    attn_b 32M..40M, WT 40M..46M, owb 46M..48M.  (needs 48MB)

typedef __bf16 bf16;
typedef float f32x4 __attribute__((ext_vector_type(4)));
typedef float float4v __attribute__((ext_vector_type(4)));
typedef bf16 bf16x8 __attribute__((ext_vector_type(8)));
typedef bf16 bf16x4 __attribute__((ext_vector_type(4)));

// ---------------- prep kernels ----------------

// dst[sec][j][i] = (bf16) src[sec*1024 + i][j]   (per-1024x1024-section transpose)
__global__ __launch_bounds__(256) void transpose_f32_to_bf16(
    const float* __restrict__ src, bf16* __restrict__ dst, int dim) {
  __shared__ bf16 tile[64][72];
  int sec = blockIdx.z;
  int i0 = blockIdx.y * 64, j0 = blockIdx.x * 64;
  const float* s = src + (long)sec * dim * dim;
  bf16* d = dst + (long)sec * dim * dim;
  int t = threadIdx.x;
#pragma unroll
  for (int p = 0; p < 4; p++) {
    int ri = (t >> 4) + p * 16, cj = (t & 15) * 4;
    float4v v = *(const float4v*)(s + (long)(i0 + ri) * dim + j0 + cj);
    bf16x4 bv = { (bf16)v.x, (bf16)v.y, (bf16)v.z, (bf16)v.w };
    *(bf16x4*)&tile[ri][cj] = bv;
  }
  __syncthreads();
#pragma unroll
  for (int p = 0; p < 4; p++) {
    int rj = (t >> 4) + p * 16, ci = (t & 15) * 4;
    bf16x4 bv = { tile[ci][rj], tile[ci + 1][rj], tile[ci + 2][rj], tile[ci + 3][rj] };
    *(bf16x4*)&d[(long)(j0 + rj) * dim + i0 + ci] = bv;
  }
}

__global__ __launch_bounds__(256) void conv_f32_bf16(
    const float* __restrict__ src, bf16* __restrict__ dst, int n) {
  int i = (blockIdx.x * 256 + threadIdx.x) * 4;
  if (i < n) {
    float4v v = *(const float4v*)(src + i);
    bf16x4 bv = { (bf16)v.x, (bf16)v.y, (bf16)v.z, (bf16)v.w };
    *(bf16x4*)&dst[i] = bv;
  }
}

// vT[(b*1024 + j)*1024 + s] = vb[(s*4 + b)*1024 + j]
__global__ __launch_bounds__(256) void transpose_v(
    const bf16* __restrict__ vb, bf16* __restrict__ vT) {
  __shared__ bf16 tile[64][72];
  int b = blockIdx.z;
  int s0 = blockIdx.x * 64, j0 = blockIdx.y * 64;
  int t = threadIdx.x;
#pragma unroll
  for (int p = 0; p < 2; p++) {
    int si = (t >> 3) + p * 32, jj = (t & 7) * 8;
    bf16x8 v = *(const bf16x8*)&vb[((long)(s0 + si) * 4 + b) * 1024 + j0 + jj];
    *(bf16x8*)&tile[si][jj] = v;
  }
  __syncthreads();
#pragma unroll
  for (int p = 0; p < 2; p++) {
    int jj = (t >> 3) + p * 32, si = (t & 7) * 8;
    bf16 tmp[8];
#pragma unroll
    for (int q = 0; q < 8; q++) tmp[q] = tile[si + q][jj];
    *(bf16x8*)&vT[((long)b * 1024 + j0 + jj) * 1024 + s0 + si] = *(bf16x8*)tmp;
  }
}

// ---------------- shared NT GEMM body ----------------
// C[m][n] = scale * ( sum_k A[m][k]*B[n][k] + bias[n] ),  128x128 tile, BK=32.
template <bool A_F32, bool C_BF16>
__device__ __forceinline__ void gemm_body(
    const void* __restrict__ Av, long lda,
    const bf16* __restrict__ B, long ldb,
    void* __restrict__ Cv, long ldc,
    const float* __restrict__ bias, float scale, int K, int m0, int n0) {
  __shared__ bf16 sA[128][40];  // +8 pad
  __shared__ bf16 sB[128][40];
  int t = threadIdx.x;
  int w = t >> 6, lane = t & 63, r = lane & 15, g = lane >> 4;
  int mq = (w >> 1) * 64, nq = (w & 1) * 64;

  f32x4 acc[4][4];
#pragma unroll
  for (int mi = 0; mi < 4; mi++)
#pragma unroll
    for (int ni = 0; ni < 4; ni++) acc[mi][ni] = (f32x4){0.f, 0.f, 0.f, 0.f};

  for (int k0 = 0; k0 < K; k0 += 32) {
    if (A_F32) {
      const float* Ap = (const float*)Av;
      int row = t >> 3, col = (t & 7) * 4;
#pragma unroll
      for (int p = 0; p < 4; p++) {
        float4v v = *(const float4v*)(Ap + (long)(m0 + row + p * 32) * lda + k0 + col);
        bf16x4 bv = { (bf16)v.x, (bf16)v.y, (bf16)v.z, (bf16)v.w };
        *(bf16x4*)&sA[row + p * 32][col] = bv;
      }
    } else {
      const bf16* Ap = (const bf16*)Av;
      int row = t >> 2, col = (t & 3) * 8;
#pragma unroll
      for (int p = 0; p < 2; p++) {
        bf16x8 v = *(const bf16x8*)(Ap + (long)(m0 + row + p * 64) * lda + k0 + col);
        *(bf16x8*)&sA[row + p * 64][col] = v;
      }
    }
    {
      int row = t >> 2, col = (t & 3) * 8;
#pragma unroll
      for (int p = 0; p < 2; p++) {
        bf16x8 v = *(const bf16x8*)(B + (long)(n0 + row + p * 64) * ldb + k0 + col);
        *(bf16x8*)&sB[row + p * 64][col] = v;
      }
    }
    __syncthreads();
    bf16x8 af[4], bfr[4];
#pragma unroll
    for (int mi = 0; mi < 4; mi++) af[mi] = *(bf16x8*)&sA[mq + mi * 16 + r][g * 8];
#pragma unroll
    for (int ni = 0; ni < 4; ni++) bfr[ni] = *(bf16x8*)&sB[nq + ni * 16 + r][g * 8];
#pragma unroll
    for (int mi = 0; mi < 4; mi++)
#pragma unroll
      for (int ni = 0; ni < 4; ni++)
        acc[mi][ni] = __builtin_amdgcn_mfma_f32_16x16x32_bf16(af[mi], bfr[ni], acc[mi][ni], 0, 0, 0);
    __syncthreads();
  }

#pragma unroll
  for (int mi = 0; mi < 4; mi++)
#pragma unroll
    for (int ni = 0; ni < 4; ni++) {
      int col = n0 + nq + ni * 16 + r;
      float bv = bias ? bias[col] : 0.f;
#pragma unroll
      for (int j = 0; j < 4; j++) {
        int row = m0 + mq + mi * 16 + g * 4 + j;
        float val = (acc[mi][ni][j] + bv) * scale;
        if (C_BF16)
          ((bf16*)Cv)[(long)row * ldc + col] = (bf16)val;
        else
          ((float*)Cv)[(long)row * ldc + col] = val;
      }
    }
}

template <bool A_F32, bool C_BF16>
__global__ __launch_bounds__(256) void gemm_nt(
    const void* __restrict__ Av, long lda, long sAz,
    const bf16* __restrict__ B, long ldb, long sBz,
    void* __restrict__ Cv, long ldc, long sCz,
    const float* __restrict__ bias, float scale, int K) {
  int z = blockIdx.z;
  const char* Ap = (const char*)Av + (long)z * sAz * (A_F32 ? 4 : 2);
  const bf16* Bp = B + (long)z * sBz;
  char* Cp = (char*)Cv + (long)z * sCz * (C_BF16 ? 2 : 4);
  gemm_body<A_F32, C_BF16>(Ap, lda, Bp, ldb, Cp, ldc, bias, scale, K,
                           blockIdx.y * 128, blockIdx.x * 128);
}

// fused q/k/v projection: z selects input & weight section
__global__ __launch_bounds__(256) void gemm_proj(
    const float* __restrict__ q, const float* __restrict__ k,
    const float* __restrict__ v, const bf16* __restrict__ WT,
    const float* __restrict__ bias, bf16* __restrict__ out) {
  int z = blockIdx.z;
  const float* A = (z == 0) ? q : ((z == 1) ? k : v);
  const bf16* B = WT + (long)z * 1048576;
  const float* bz = bias + z * 1024;
  bf16* C = out + (long)z * 4194304;
  float scale = (z == 0) ? 0.125f : 1.0f;
  gemm_body<true, true>(A, 1024, B, 1024, C, 1024, bz, scale, 1024,
                        blockIdx.y * 128, blockIdx.x * 128);
}

// ---------------- fused dual-softmax flash attention (v2) ----------------
// grid (B*H, T/64); 4 waves, wave w owns 16 t-rows. NO barriers:
// P exchange buffer is wave-private; swapped QK^T makes score rows lane-local.
__global__ __launch_bounds__(256, 4) void attn_fused(
    const bf16* __restrict__ qb, const bf16* __restrict__ kb,
    const bf16* __restrict__ vT, bf16* __restrict__ attn_b) {
  // per-wave P buffers, 136-elem row stride (272 B): write b64 4/bank, read b128 8/bank (min)
  __shared__ bf16 sPp[4][16][136];
  __shared__ bf16 sPn[4][16][136];
  int bh = blockIdx.x;
  int b = bh >> 4, h = bh & 15;
  int t0 = blockIdx.y * 64;
  int t = threadIdx.x, w = t >> 6, lane = t & 63, r = lane & 15, g = lane >> 4;
  int tw = t0 + w * 16;

  // Q fragment (B-operand of swapped QK^T): lane (r,g) holds Q[t=tw+r][kk*32+g*8 ..+7]
  bf16x8 aq[2];
#pragma unroll
  for (int kk = 0; kk < 2; kk++)
    aq[kk] = *(const bf16x8*)&qb[((long)(tw + r) * 4 + b) * 1024 + h * 64 + kk * 32 + g * 8];

  // stats per t = r (replicated across g); O accumulators per t = g*4+j
  float m_p = -1e30f, l_p = 0.f, m_n = -1e30f, l_n = 0.f;
  f32x4 o_p[2], o_n[2];
#pragma unroll
  for (int ni = 0; ni < 2; ni++) {
    o_p[ni] = (f32x4){0.f, 0.f, 0.f, 0.f};
    o_n[ni] = (f32x4){0.f, 0.f, 0.f, 0.f};
  }

  const long kbase = (long)b * 1024 + h * 64 + g * 8;      // + s*4096
  const long vbase = ((long)b * 1024 + h * 32 + r) * 1024 + g * 8;
  const long vnoff = 512L * 1024;                          // decorr half of vT

#pragma unroll 1
  for (int st = 0; st < 8; st++) {
    int sb = st * 128;
    // ---- QK^T swapped: sc[sf][j] = score[t=r][s = sb + sf*16 + g*4 + j] ----
    f32x4 sc[8];
#pragma unroll
    for (int sf = 0; sf < 8; sf++) {
      const bf16* kp = kb + (long)(sb + sf * 16 + r) * 4096 + kbase;
      bf16x8 k0 = *(const bf16x8*)kp;
      bf16x8 k1 = *(const bf16x8*)(kp + 32);
      f32x4 z = (f32x4){0.f, 0.f, 0.f, 0.f};
      z = __builtin_amdgcn_mfma_f32_16x16x32_bf16(k0, aq[0], z, 0, 0, 0);
      z = __builtin_amdgcn_mfma_f32_16x16x32_bf16(k1, aq[1], z, 0, 0, 0);
      sc[sf] = z;
    }
    // ---- dual online softmax for row t=r: in-reg reduce + 2 shfl ----
    float mx = sc[0][0], mn = sc[0][0];
#pragma unroll
    for (int sf = 0; sf < 8; sf++)
#pragma unroll
      for (int j = 0; j < 4; j++) {
        mx = fmaxf(mx, sc[sf][j]);
        mn = fminf(mn, sc[sf][j]);
      }
    mx = fmaxf(mx, __shfl_xor(mx, 16)); mx = fmaxf(mx, __shfl_xor(mx, 32));
    mn = fminf(mn, __shfl_xor(mn, 16)); mn = fminf(mn, __shfl_xor(mn, 32));
    float np = fmaxf(m_p, mx), nn = fmaxf(m_n, -mn);
    float alp = __expf(m_p - np), aln = __expf(m_n - nn);
    m_p = np; m_n = nn;
    float sp = 0.f, sn = 0.f;
#pragma unroll
    for (int sf = 0; sf < 8; sf++) {
      float e0 = __expf(sc[sf][0] - np), e1 = __expf(sc[sf][1] - np);
      float e2 = __expf(sc[sf][2] - np), e3 = __expf(sc[sf][3] - np);
      sp += (e0 + e1) + (e2 + e3);
      bf16x4 pv = { (bf16)e0, (bf16)e1, (bf16)e2, (bf16)e3 };
      *(bf16x4*)&sPp[w][r][sf * 16 + g * 4] = pv;
      float f0 = __expf(-sc[sf][0] - nn), f1 = __expf(-sc[sf][1] - nn);
      float f2 = __expf(-sc[sf][2] - nn), f3 = __expf(-sc[sf][3] - nn);
      sn += (f0 + f1) + (f2 + f3);
      bf16x4 fv = { (bf16)f0, (bf16)f1, (bf16)f2, (bf16)f3 };
      *(bf16x4*)&sPn[w][r][sf * 16 + g * 4] = fv;
    }
    sp += __shfl_xor(sp, 16); sp += __shfl_xor(sp, 32);
    sn += __shfl_xor(sn, 16); sn += __shfl_xor(sn, 32);
    l_p = l_p * alp + sp;
    l_n = l_n * aln + sn;
    // ---- rescale O (needs alpha for t = g*4+j, held by lane g*16 + g*4+j) ----
#pragma unroll
    for (int j = 0; j < 4; j++) {
      float aj = __shfl(alp, g * 20 + j);
      float bj = __shfl(aln, g * 20 + j);
      o_p[0][j] *= aj; o_p[1][j] *= aj;
      o_n[0][j] *= bj; o_n[1][j] *= bj;
    }
    // ---- PV: A-frag from wave-private LDS (b128), B-frag from vT ----
#pragma unroll
    for (int c = 0; c < 4; c++) {
      bf16x8 apP = *(bf16x8*)&sPp[w][r][c * 32 + g * 8];
      bf16x8 apN = *(bf16x8*)&sPn[w][r][c * 32 + g * 8];
#pragma unroll
      for (int ni = 0; ni < 2; ni++) {
        bf16x8 vP = *(const bf16x8*)&vT[vbase + (long)ni * 16384 + sb + c * 32];
        bf16x8 vN = *(const bf16x8*)&vT[vbase + vnoff + (long)ni * 16384 + sb + c * 32];
        o_p[ni] = __builtin_amdgcn_mfma_f32_16x16x32_bf16(apP, vP, o_p[ni], 0, 0, 0);
        o_n[ni] = __builtin_amdgcn_mfma_f32_16x16x32_bf16(apN, vN, o_n[ni], 0, 0, 0);
      }
    }
  }

  // ---- epilogue: divide by l (per t = g*4+j) and store ----
#pragma unroll
  for (int j = 0; j < 4; j++) {
    float lpj = __shfl(l_p, g * 20 + j);
    float lnj = __shfl(l_n, g * 20 + j);
    float rp = 1.0f / lpj, rn = 1.0f / lnj;
    int trow = tw + g * 4 + j;
    long base = ((long)trow * 4 + b) * 1024 + h * 64;
#pragma unroll
    for (int ni = 0; ni < 2; ni++) {
      attn_b[base + ni * 16 + r] = (bf16)(o_p[ni][j] * rp);
      attn_b[base + 32 + ni * 16 + r] = (bf16)(o_n[ni][j] * rn);
    }
  }
}

// ---------------- launcher ----------------
extern "C" void kernel_launch(void* const* d_in, const int* in_sizes, int n_in,
                              void* d_out, int out_size, void* d_ws, size_t ws_size,
                              hipStream_t stream) {
  (void)in_sizes; (void)n_in; (void)out_size; (void)ws_size;
  const float* query = (const float*)d_in[0];
  const float* key   = (const float*)d_in[1];
  const float* value = (const float*)d_in[2];
  const float* W     = (const float*)d_in[3];
  const float* bias  = (const float*)d_in[4];
  const float* out_w = (const float*)d_in[5];
  const float* out_b = (const float*)d_in[6];

  char* ws = (char*)d_ws;
  const long MB = 1 << 20;
  bf16* qb  = (bf16*)(ws + 0 * MB);
  bf16* kb  = (bf16*)(ws + 8 * MB);
  bf16* vb  = (bf16*)(ws + 16 * MB);
  bf16* vT  = (bf16*)(ws + 24 * MB);
  bf16* ab  = (bf16*)(ws + 32 * MB);
  bf16* WT  = (bf16*)(ws + 40 * MB);
  bf16* owb = (bf16*)(ws + 46 * MB);
  float* out_attn = (float*)d_out;
  float* out_avg  = (float*)d_out + (size_t)4 * 1024 * 1024;
  const long M1 = 1024L * 1024L;

  transpose_f32_to_bf16<<<dim3(16, 16, 3), 256, 0, stream>>>(W, WT, 1024);
  conv_f32_bf16<<<dim3(1024), 256, 0, stream>>>(out_w, owb, 1024 * 1024);

  // fused projections: q (scaled 0.125), k, v — one launch, 768 blocks
  gemm_proj<<<dim3(8, 32, 3), 256, 0, stream>>>(query, key, value, WT, bias, qb);

  transpose_v<<<dim3(16, 16, 4), 256, 0, stream>>>(vb, vT);

  // avg_w[b,t,s] = (1/16) * sum_e q_scaled[t,b,e] * k[s,b,e]
  gemm_nt<false, false><<<dim3(8, 8, 4), 256, 0, stream>>>(
      qb, 4096, 1024, kb, 4096, 1024, out_avg, 1024, M1, nullptr, 1.f / 16.f, 1024);

  attn_fused<<<dim3(64, 16), 256, 0, stream>>>(qb, kb, vT, ab);

  // out projection: C = attn @ out_w^T + out_b
  gemm_nt<false, false><<<dim3(8, 32, 1), 256, 0, stream>>>(
      ab, 1024, 0, owb, 1024, 0, out_attn, 1024, 0, out_b, 1.0f, 1024);
}

// Round 3
// 244.709 us; speedup vs baseline: 1.3105x; 1.0992x over previous
//
#include <hip/hip_runtime.h>
#include <hip/hip_bf16.h>

// Problem constants: E=1024, H=16, HD=64, T=1024, B=4, S=1024.
// d_in: 0 query(T,B,E) f32, 1 key(S,B,E), 2 value(S,B,E), 3 in_proj_weight(3E,E),
//       4 in_proj_bias(3E), 5 out_w(E,E), 6 out_b(E).
// d_out: attn(T,B,E) f32 [4M] then avg_w(B,T,S) f32 [4M].
// ws layout (bytes): qb 0..8M, kb 8M..16M, vb 16M..24M, vT 24M..32M,
//                    attn_b 32M..40M, WT 40M..46M, owb 46M..48M.  (needs 48MB)

typedef __bf16 bf16;
typedef float f32x4 __attribute__((ext_vector_type(4)));
typedef float float4v __attribute__((ext_vector_type(4)));
typedef bf16 bf16x8 __attribute__((ext_vector_type(8)));
typedef bf16 bf16x4 __attribute__((ext_vector_type(4)));

// ---------------- prep kernels ----------------

// dst[sec][j][i] = (bf16) src[sec*1024 + i][j]   (per-1024x1024-section transpose)
__global__ __launch_bounds__(256) void transpose_f32_to_bf16(
    const float* __restrict__ src, bf16* __restrict__ dst, int dim) {
  __shared__ bf16 tile[64][72];
  int sec = blockIdx.z;
  int i0 = blockIdx.y * 64, j0 = blockIdx.x * 64;
  const float* s = src + (long)sec * dim * dim;
  bf16* d = dst + (long)sec * dim * dim;
  int t = threadIdx.x;
#pragma unroll
  for (int p = 0; p < 4; p++) {
    int ri = (t >> 4) + p * 16, cj = (t & 15) * 4;
    float4v v = *(const float4v*)(s + (long)(i0 + ri) * dim + j0 + cj);
    bf16x4 bv = { (bf16)v.x, (bf16)v.y, (bf16)v.z, (bf16)v.w };
    *(bf16x4*)&tile[ri][cj] = bv;
  }
  __syncthreads();
#pragma unroll
  for (int p = 0; p < 4; p++) {
    int rj = (t >> 4) + p * 16, ci = (t & 15) * 4;
    bf16x4 bv = { tile[ci][rj], tile[ci + 1][rj], tile[ci + 2][rj], tile[ci + 3][rj] };
    *(bf16x4*)&d[(long)(j0 + rj) * dim + i0 + ci] = bv;
  }
}

__global__ __launch_bounds__(256) void conv_f32_bf16(
    const float* __restrict__ src, bf16* __restrict__ dst, int n) {
  int i = (blockIdx.x * 256 + threadIdx.x) * 4;
  if (i < n) {
    float4v v = *(const float4v*)(src + i);
    bf16x4 bv = { (bf16)v.x, (bf16)v.y, (bf16)v.z, (bf16)v.w };
    *(bf16x4*)&dst[i] = bv;
  }
}

// vT[(b*1024 + j)*1024 + s] = vb[(s*4 + b)*1024 + j]
__global__ __launch_bounds__(256) void transpose_v(
    const bf16* __restrict__ vb, bf16* __restrict__ vT) {
  __shared__ bf16 tile[64][72];
  int b = blockIdx.z;
  int s0 = blockIdx.x * 64, j0 = blockIdx.y * 64;
  int t = threadIdx.x;
#pragma unroll
  for (int p = 0; p < 2; p++) {
    int si = (t >> 3) + p * 32, jj = (t & 7) * 8;
    bf16x8 v = *(const bf16x8*)&vb[((long)(s0 + si) * 4 + b) * 1024 + j0 + jj];
    *(bf16x8*)&tile[si][jj] = v;
  }
  __syncthreads();
#pragma unroll
  for (int p = 0; p < 2; p++) {
    int jj = (t >> 3) + p * 32, si = (t & 7) * 8;
    bf16 tmp[8];
#pragma unroll
    for (int q = 0; q < 8; q++) tmp[q] = tile[si + q][jj];
    *(bf16x8*)&vT[((long)b * 1024 + j0 + jj) * 1024 + s0 + si] = *(bf16x8*)tmp;
  }
}

// ---------------- shared NT GEMM body (512 threads, 8 waves, 128x128 tile) ----
// C[m][n] = scale * ( sum_k A[m][k]*B[n][k] + bias[n] ),  BK=32.
// wave w owns a 32x64 sub-tile: mq=(w>>1)*32, nq=(w&1)*64, acc[2][4].
template <bool A_F32, bool C_BF16>
__device__ __forceinline__ void gemm_body(
    const void* __restrict__ Av, long lda,
    const bf16* __restrict__ B, long ldb,
    void* __restrict__ Cv, long ldc,
    const float* __restrict__ bias, float scale, int K, int m0, int n0) {
  __shared__ bf16 sA[128][40];  // +8 pad
  __shared__ bf16 sB[128][40];
  int t = threadIdx.x;
  int w = t >> 6, lane = t & 63, r = lane & 15, g = lane >> 4;
  int mq = (w >> 1) * 32, nq = (w & 1) * 64;

  f32x4 acc[2][4];
#pragma unroll
  for (int mi = 0; mi < 2; mi++)
#pragma unroll
    for (int ni = 0; ni < 4; ni++) acc[mi][ni] = (f32x4){0.f, 0.f, 0.f, 0.f};

  for (int k0 = 0; k0 < K; k0 += 32) {
    if (A_F32) {
      const float* Ap = (const float*)Av;
      int row = t >> 3, col = (t & 7) * 4;
#pragma unroll
      for (int p = 0; p < 2; p++) {
        float4v v = *(const float4v*)(Ap + (long)(m0 + row + p * 64) * lda + k0 + col);
        bf16x4 bv = { (bf16)v.x, (bf16)v.y, (bf16)v.z, (bf16)v.w };
        *(bf16x4*)&sA[row + p * 64][col] = bv;
      }
    } else {
      const bf16* Ap = (const bf16*)Av;
      int row = t >> 2, col = (t & 3) * 8;
      bf16x8 v = *(const bf16x8*)(Ap + (long)(m0 + row) * lda + k0 + col);
      *(bf16x8*)&sA[row][col] = v;
    }
    {
      int row = t >> 2, col = (t & 3) * 8;
      bf16x8 v = *(const bf16x8*)(B + (long)(n0 + row) * ldb + k0 + col);
      *(bf16x8*)&sB[row][col] = v;
    }
    __syncthreads();
    bf16x8 af[2], bfr[4];
#pragma unroll
    for (int mi = 0; mi < 2; mi++) af[mi] = *(bf16x8*)&sA[mq + mi * 16 + r][g * 8];
#pragma unroll
    for (int ni = 0; ni < 4; ni++) bfr[ni] = *(bf16x8*)&sB[nq + ni * 16 + r][g * 8];
#pragma unroll
    for (int mi = 0; mi < 2; mi++)
#pragma unroll
      for (int ni = 0; ni < 4; ni++)
        acc[mi][ni] = __builtin_amdgcn_mfma_f32_16x16x32_bf16(af[mi], bfr[ni], acc[mi][ni], 0, 0, 0);
    __syncthreads();
  }

#pragma unroll
  for (int mi = 0; mi < 2; mi++)
#pragma unroll
    for (int ni = 0; ni < 4; ni++) {
      int col = n0 + nq + ni * 16 + r;
      float bv = bias ? bias[col] : 0.f;
#pragma unroll
      for (int j = 0; j < 4; j++) {
        int row = m0 + mq + mi * 16 + g * 4 + j;
        float val = (acc[mi][ni][j] + bv) * scale;
        if (C_BF16)
          ((bf16*)Cv)[(long)row * ldc + col] = (bf16)val;
        else
          ((float*)Cv)[(long)row * ldc + col] = val;
      }
    }
}

template <bool A_F32, bool C_BF16>
__global__ __launch_bounds__(512) void gemm_nt(
    const void* __restrict__ Av, long lda, long sAz,
    const bf16* __restrict__ B, long ldb, long sBz,
    void* __restrict__ Cv, long ldc, long sCz,
    const float* __restrict__ bias, float scale, int K) {
  int z = blockIdx.z;
  const char* Ap = (const char*)Av + (long)z * sAz * (A_F32 ? 4 : 2);
  const bf16* Bp = B + (long)z * sBz;
  char* Cp = (char*)Cv + (long)z * sCz * (C_BF16 ? 2 : 4);
  gemm_body<A_F32, C_BF16>(Ap, lda, Bp, ldb, Cp, ldc, bias, scale, K,
                           blockIdx.y * 128, blockIdx.x * 128);
}

// fused q/k/v projection: z selects input & weight section
__global__ __launch_bounds__(512) void gemm_proj(
    const float* __restrict__ q, const float* __restrict__ k,
    const float* __restrict__ v, const bf16* __restrict__ WT,
    const float* __restrict__ bias, bf16* __restrict__ out) {
  int z = blockIdx.z;
  const float* A = (z == 0) ? q : ((z == 1) ? k : v);
  const bf16* B = WT + (long)z * 1048576;
  const float* bz = bias + z * 1024;
  bf16* C = out + (long)z * 4194304;
  float scale = (z == 0) ? 0.125f : 1.0f;
  gemm_body<true, true>(A, 1024, B, 1024, C, 1024, bz, scale, 1024,
                        blockIdx.y * 128, blockIdx.x * 128);
}

// ---------------- fused dual-softmax flash attention (v3) ----------------
// grid (B*H, T/64); 4 waves, wave w owns 16 t-rows. NO barriers:
// P exchange buffer is wave-private; swapped QK^T makes score rows lane-local.
// s-tile = 64 -> sc[4] keeps live VGPRs ~105 (<128): no spills (v2 spilled).
__global__ __launch_bounds__(256, 4) void attn_fused(
    const bf16* __restrict__ qb, const bf16* __restrict__ kb,
    const bf16* __restrict__ vT, bf16* __restrict__ attn_b) {
  __shared__ bf16 sPp[4][16][72];
  __shared__ bf16 sPn[4][16][72];
  int bh = blockIdx.x;
  int b = bh >> 4, h = bh & 15;
  int t0 = blockIdx.y * 64;
  int t = threadIdx.x, w = t >> 6, lane = t & 63, r = lane & 15, g = lane >> 4;
  int tw = t0 + w * 16;

  // Q fragment (B-operand of swapped QK^T): lane (r,g) holds Q[t=tw+r][kk*32+g*8 ..+7]
  bf16x8 aq[2];
#pragma unroll
  for (int kk = 0; kk < 2; kk++)
    aq[kk] = *(const bf16x8*)&qb[((long)(tw + r) * 4 + b) * 1024 + h * 64 + kk * 32 + g * 8];

  // stats per t = r (replicated across g); O accumulators per t = g*4+j
  float m_p = -1e30f, l_p = 0.f, m_n = -1e30f, l_n = 0.f;
  f32x4 o_p[2], o_n[2];
#pragma unroll
  for (int ni = 0; ni < 2; ni++) {
    o_p[ni] = (f32x4){0.f, 0.f, 0.f, 0.f};
    o_n[ni] = (f32x4){0.f, 0.f, 0.f, 0.f};
  }

  const long kbase = (long)b * 1024 + h * 64 + g * 8;      // + s*4096
  const long vbase = ((long)b * 1024 + h * 32 + r) * 1024 + g * 8;
  const long vnoff = 512L * 1024;                          // decorr half of vT

#pragma unroll 1
  for (int st = 0; st < 16; st++) {
    int sb = st * 64;
    // ---- QK^T swapped: sc[sf][j] = score[t=r][s = sb + sf*16 + g*4 + j] ----
    f32x4 sc[4];
#pragma unroll
    for (int sf = 0; sf < 4; sf++) {
      const bf16* kp = kb + (long)(sb + sf * 16 + r) * 4096 + kbase;
      bf16x8 k0 = *(const bf16x8*)kp;
      bf16x8 k1 = *(const bf16x8*)(kp + 32);
      f32x4 z = (f32x4){0.f, 0.f, 0.f, 0.f};
      z = __builtin_amdgcn_mfma_f32_16x16x32_bf16(k0, aq[0], z, 0, 0, 0);
      z = __builtin_amdgcn_mfma_f32_16x16x32_bf16(k1, aq[1], z, 0, 0, 0);
      sc[sf] = z;
    }
    // ---- dual online softmax for row t=r: in-reg reduce + 2 shfl ----
    float mx = sc[0][0], mn = sc[0][0];
#pragma unroll
    for (int sf = 0; sf < 4; sf++)
#pragma unroll
      for (int j = 0; j < 4; j++) {
        mx = fmaxf(mx, sc[sf][j]);
        mn = fminf(mn, sc[sf][j]);
      }
    mx = fmaxf(mx, __shfl_xor(mx, 16)); mx = fmaxf(mx, __shfl_xor(mx, 32));
    mn = fminf(mn, __shfl_xor(mn, 16)); mn = fminf(mn, __shfl_xor(mn, 32));
    float np = fmaxf(m_p, mx), nn = fmaxf(m_n, -mn);
    float alp = __expf(m_p - np), aln = __expf(m_n - nn);
    m_p = np; m_n = nn;
    float sp = 0.f, sn = 0.f;
#pragma unroll
    for (int sf = 0; sf < 4; sf++) {
      float e0 = __expf(sc[sf][0] - np), e1 = __expf(sc[sf][1] - np);
      float e2 = __expf(sc[sf][2] - np), e3 = __expf(sc[sf][3] - np);
      sp += (e0 + e1) + (e2 + e3);
      bf16x4 pv = { (bf16)e0, (bf16)e1, (bf16)e2, (bf16)e3 };
      *(bf16x4*)&sPp[w][r][sf * 16 + g * 4] = pv;
      float f0 = __expf(-sc[sf][0] - nn), f1 = __expf(-sc[sf][1] - nn);
      float f2 = __expf(-sc[sf][2] - nn), f3 = __expf(-sc[sf][3] - nn);
      sn += (f0 + f1) + (f2 + f3);
      bf16x4 fv = { (bf16)f0, (bf16)f1, (bf16)f2, (bf16)f3 };
      *(bf16x4*)&sPn[w][r][sf * 16 + g * 4] = fv;
    }
    sp += __shfl_xor(sp, 16); sp += __shfl_xor(sp, 32);
    sn += __shfl_xor(sn, 16); sn += __shfl_xor(sn, 32);
    l_p = l_p * alp + sp;
    l_n = l_n * aln + sn;
    // ---- rescale O (alpha for t = g*4+j is held by lane g*16 + g*4+j) ----
#pragma unroll
    for (int j = 0; j < 4; j++) {
      float aj = __shfl(alp, g * 20 + j);
      float bj = __shfl(aln, g * 20 + j);
      o_p[0][j] *= aj; o_p[1][j] *= aj;
      o_n[0][j] *= bj; o_n[1][j] *= bj;
    }
    // ---- PV: A-frag from wave-private LDS (b128), B-frag from vT ----
#pragma unroll
    for (int c = 0; c < 2; c++) {
      bf16x8 apP = *(bf16x8*)&sPp[w][r][c * 32 + g * 8];
      bf16x8 apN = *(bf16x8*)&sPn[w][r][c * 32 + g * 8];
#pragma unroll
      for (int ni = 0; ni < 2; ni++) {
        bf16x8 vP = *(const bf16x8*)&vT[vbase + (long)ni * 16384 + sb + c * 32];
        bf16x8 vN = *(const bf16x8*)&vT[vbase + vnoff + (long)ni * 16384 + sb + c * 32];
        o_p[ni] = __builtin_amdgcn_mfma_f32_16x16x32_bf16(apP, vP, o_p[ni], 0, 0, 0);
        o_n[ni] = __builtin_amdgcn_mfma_f32_16x16x32_bf16(apN, vN, o_n[ni], 0, 0, 0);
      }
    }
  }

  // ---- epilogue: divide by l (per t = g*4+j) and store ----
#pragma unroll
  for (int j = 0; j < 4; j++) {
    float lpj = __shfl(l_p, g * 20 + j);
    float lnj = __shfl(l_n, g * 20 + j);
    float rp = 1.0f / lpj, rn = 1.0f / lnj;
    int trow = tw + g * 4 + j;
    long base = ((long)trow * 4 + b) * 1024 + h * 64;
#pragma unroll
    for (int ni = 0; ni < 2; ni++) {
      attn_b[base + ni * 16 + r] = (bf16)(o_p[ni][j] * rp);
      attn_b[base + 32 + ni * 16 + r] = (bf16)(o_n[ni][j] * rn);
    }
  }
}

// ---------------- launcher ----------------
extern "C" void kernel_launch(void* const* d_in, const int* in_sizes, int n_in,
                              void* d_out, int out_size, void* d_ws, size_t ws_size,
                              hipStream_t stream) {
  (void)in_sizes; (void)n_in; (void)out_size; (void)ws_size;
  const float* query = (const float*)d_in[0];
  const float* key   = (const float*)d_in[1];
  const float* value = (const float*)d_in[2];
  const float* W     = (const float*)d_in[3];
  const float* bias  = (const float*)d_in[4];
  const float* out_w = (const float*)d_in[5];
  const float* out_b = (const float*)d_in[6];

  char* ws = (char*)d_ws;
  const long MB = 1 << 20;
  bf16* qb  = (bf16*)(ws + 0 * MB);
  bf16* kb  = (bf16*)(ws + 8 * MB);
  bf16* vb  = (bf16*)(ws + 16 * MB);
  bf16* vT  = (bf16*)(ws + 24 * MB);
  bf16* ab  = (bf16*)(ws + 32 * MB);
  bf16* WT  = (bf16*)(ws + 40 * MB);
  bf16* owb = (bf16*)(ws + 46 * MB);
  float* out_attn = (float*)d_out;
  float* out_avg  = (float*)d_out + (size_t)4 * 1024 * 1024;
  const long M1 = 1024L * 1024L;

  transpose_f32_to_bf16<<<dim3(16, 16, 3), 256, 0, stream>>>(W, WT, 1024);
  conv_f32_bf16<<<dim3(1024), 256, 0, stream>>>(out_w, owb, 1024 * 1024);

  // fused projections: q (scaled 0.125), k, v — one launch, 768 blocks x 8 waves
  gemm_proj<<<dim3(8, 32, 3), 512, 0, stream>>>(query, key, value, WT, bias, qb);

  transpose_v<<<dim3(16, 16, 4), 256, 0, stream>>>(vb, vT);

  // avg_w[b,t,s] = (1/16) * sum_e q_scaled[t,b,e] * k[s,b,e]
  gemm_nt<false, false><<<dim3(8, 8, 4), 512, 0, stream>>>(
      qb, 4096, 1024, kb, 4096, 1024, out_avg, 1024, M1, nullptr, 1.f / 16.f, 1024);

  attn_fused<<<dim3(64, 16), 256, 0, stream>>>(qb, kb, vT, ab);

  // out projection: C = attn @ out_w^T + out_b
  gemm_nt<false, false><<<dim3(8, 32, 1), 512, 0, stream>>>(
      ab, 1024, 0, owb, 1024, 0, out_attn, 1024, 0, out_b, 1.0f, 1024);
}